// Round 12
// baseline (23731.781 us; speedup 1.0000x reference)
//
#include <hip/hip_runtime.h>
#include <hip/hip_bf16.h>
#include <math.h>

#define BB 256
#define TT 256
#define INW 256
#define HH 1024
#define LL 8
#define CSW 10
#define OUTW 64
#define GG 4112
#define KXP 896            // x-part GEMM K: 3*288 = 864 padded
#define NPAD 4224          // 4112 padded
#define BH2 (BB * 2048)    // h ring slot stride: [b][0..1023]=hi, [1024..2047]=lo

typedef __attribute__((ext_vector_type(8))) short short8;
typedef __attribute__((ext_vector_type(4))) float f32x4;

__device__ __forceinline__ float bf2f(ushort u) {
    union { float f; unsigned int i; } v; v.i = ((unsigned int)u) << 16; return v.f;
}
__device__ __forceinline__ ushort f2bf(float f) {
    __hip_bfloat16 h = __float2bfloat16(f);
    return *(ushort*)&h;
}
__device__ __forceinline__ float sigf(float v) { return 1.0f / (1.0f + expf(-v)); }

// ================= fused per-step kernel =================
// grid 256 x 256thr. Block: ct=(bid&7)+8*((bid>>3)&3) [XCD-pinned], rt=bid>>5.
// Owns rows R0=rt*32, permuted cols P0=ct*128 (units U0=ct*32) + the 16 special
// softmax cols (computed redundantly by every block -> no cross-block exchange).
// One accumulator chains all 3 precision streams: acc += Alo*Whi + Ahi*Wlo + Ahi*Whi.
// Epilogue: softmax (rows) -> gates -> c update (global) -> h hi/lo write. No atomics.
__global__ __launch_bounds__(256) void step_fused(
    const ushort* __restrict__ WhiP, const ushort* __restrict__ WloP,
    const ushort* __restrict__ WspT, ushort* __restrict__ hR,
    float* __restrict__ cSt, const float* __restrict__ xoX,
    const float* __restrict__ bcp, float* __restrict__ dist,
    int t, int tLoc, int RING)
{
    __shared__ ushort Wh_s[160 * 36];   // [col][k] kt-tile, pad 36
    __shared__ ushort Wl_s[160 * 36];
    __shared__ ushort Ah_s[32 * 36];
    __shared__ ushort Al_s[32 * 36];
    __shared__ float  xo_s[32 * 164];   // [row][col], stride 164
    __shared__ float  fmim_s[32 * 16];  // [row][fm0-7, im0-7]
    __shared__ ushort hOut_s[32 * 32], loOut_s[32 * 32];

    const int tid = threadIdx.x, lane = tid & 63, wave = tid >> 6;
    const int bid = blockIdx.x;
    const int ct = (bid & 7) + 8 * ((bid >> 3) & 3);
    const int rt = bid >> 5;
    const int R0 = rt * 32, U0 = ct * 32, P0 = ct * 128;
    const ushort* hA = hR + (size_t)((t + 8) % RING) * BH2;

    // staging slot map: s = j*256+tid; [0,640)=Whi [640,1280)=Wlo [1280,1408)=Ah [1408,1536)=Al
    auto gfetch = [&](int kt, short8* pf) {
#pragma unroll
        for (int j = 0; j < 6; ++j) {
            int s = j * 256 + tid;
            short8 v;
            if (s < 1280) {
                bool lo = s >= 640;
                int s2 = lo ? s - 640 : s;
                int col = s2 >> 2, k8 = (s2 & 3) * 8;
                if (col < 128) {
                    const ushort* W = lo ? WloP : WhiP;
                    v = *(const short8*)(W + (size_t)(P0 + col) * 1024 + kt * 32 + k8);
                } else if (col < 144) {
                    v = *(const short8*)(WspT + (size_t)(col - 128 + (lo ? 16 : 0)) * 1024 + kt * 32 + k8);
                } else {
                    ushort* pz = (ushort*)&v;
#pragma unroll
                    for (int q = 0; q < 8; ++q) pz[q] = 0;
                }
            } else {
                bool lo = s >= 1408;
                int s2 = lo ? s - 1408 : s - 1280;
                int r = s2 >> 2, k8 = (s2 & 3) * 8;
                v = *(const short8*)(hA + (size_t)(R0 + r) * 2048 + (lo ? 1024 : 0) + kt * 32 + k8);
            }
            pf[j] = v;
        }
    };
    auto stow = [&](short8* pf) {
#pragma unroll
        for (int j = 0; j < 6; ++j) {
            int s = j * 256 + tid;
            ushort* dst;
            if (s < 640)       { dst = Wh_s + (s >> 2) * 36 + (s & 3) * 8; }
            else if (s < 1280) { int s2 = s - 640;  dst = Wl_s + (s2 >> 2) * 36 + (s2 & 3) * 8; }
            else if (s < 1408) { int s2 = s - 1280; dst = Ah_s + (s2 >> 2) * 36 + (s2 & 3) * 8; }
            else               { int s2 = s - 1408; dst = Al_s + (s2 >> 2) * 36 + (s2 & 3) * 8; }
            *(short8*)dst = pf[j];
        }
    };

    f32x4 acc[3][2] = {};      // [frag: ff0,ff0+1,special][Mfrag]
    short8 pf[6];
    gfetch(0, pf);
    const int fr = lane & 15, fk = (lane >> 4) * 8;
    const int ff0 = wave * 2;

    for (int kt = 0; kt < 32; ++kt) {
        stow(pf);
        __syncthreads();
        if (kt + 1 < 32) gfetch(kt + 1, pf);
        short8 ah0 = *(const short8*)(Ah_s + fr * 36 + fk);
        short8 ah1 = *(const short8*)(Ah_s + (16 + fr) * 36 + fk);
        short8 al0 = *(const short8*)(Al_s + fr * 36 + fk);
        short8 al1 = *(const short8*)(Al_s + (16 + fr) * 36 + fk);
#pragma unroll
        for (int fi = 0; fi < 3; ++fi) {
            int ff = (fi < 2) ? (ff0 + fi) : 8;
            short8 wh = *(const short8*)(Wh_s + (ff * 16 + fr) * 36 + fk);
            short8 wl = *(const short8*)(Wl_s + (ff * 16 + fr) * 36 + fk);
            acc[fi][0] = __builtin_amdgcn_mfma_f32_16x16x32_bf16(al0, wh, acc[fi][0], 0, 0, 0);
            acc[fi][1] = __builtin_amdgcn_mfma_f32_16x16x32_bf16(al1, wh, acc[fi][1], 0, 0, 0);
            acc[fi][0] = __builtin_amdgcn_mfma_f32_16x16x32_bf16(ah0, wl, acc[fi][0], 0, 0, 0);
            acc[fi][1] = __builtin_amdgcn_mfma_f32_16x16x32_bf16(ah1, wl, acc[fi][1], 0, 0, 0);
            acc[fi][0] = __builtin_amdgcn_mfma_f32_16x16x32_bf16(ah0, wh, acc[fi][0], 0, 0, 0);
            acc[fi][1] = __builtin_amdgcn_mfma_f32_16x16x32_bf16(ah1, wh, acc[fi][1], 0, 0, 0);
        }
        __syncthreads();
    }
    // ---- xo -> LDS (waves 1-3 write their 2 frags; wave 0 also writes special) ----
    {
        int nF = (wave == 0) ? 3 : 2;
        for (int fi = 0; fi < nF; ++fi) {
            int ff = (fi < 2) ? (ff0 + fi) : 8;
#pragma unroll
            for (int m = 0; m < 2; ++m)
#pragma unroll
                for (int j = 0; j < 4; ++j) {
                    int row = m * 16 + ((lane >> 4) << 2) + j;
                    xo_s[row * 164 + ff * 16 + fr] = acc[fi][m][j];
                }
        }
    }
    __syncthreads();
    // ---- per-row softmax/cumsum (all blocks, own rows; bit-identical across ct) ----
    if (tid < 32) {
        int r = tid;
        const float* xxs = xoX + ((size_t)tLoc * 256 + R0 + r) * NPAD + 4096;
        float xr[16];
#pragma unroll
        for (int q = 0; q < 16; ++q) xr[q] = xo_s[r * 164 + 128 + q] + xxs[q] + bcp[4096 + q];
        float m1 = -1e30f, m2 = -1e30f;
        for (int q = 0; q < 8; ++q) { m1 = fmaxf(m1, xr[q]); m2 = fmaxf(m2, xr[8 + q]); }
        float e1[8], e2[8], s1 = 0.f, s2 = 0.f;
        for (int q = 0; q < 8; ++q) {
            e1[q] = expf(xr[q] - m1); s1 += e1[q];
            e2[q] = expf(xr[8 + q] - m2); s2 += e2[q];
        }
        float s1i = 1.0f / s1, s2i = 1.0f / s2;
        float cum = 0.f, mean = 0.f;
        for (int q = 0; q < 8; ++q) { cum += e1[q] * s1i; fmim_s[r * 16 + q] = cum; mean += cum; }
        float rc = 0.f;
        for (int q = 7; q >= 0; --q) { rc += e2[q] * s2i; fmim_s[r * 16 + 8 + q] = rc; }
        if (ct == 0) dist[(size_t)t * BB + R0 + r] = 1.0f - mean * 0.125f;
    }
    __syncthreads();
    // ---- pointwise: 1024 cells, c in global, h packed via LDS ----
#pragma unroll
    for (int j = 0; j < 4; ++j) {
        int idx = tid + j * 256;
        int row = idx >> 5, u = idx & 31;
        f32x4 g  = *(const f32x4*)(xo_s + row * 164 + u * 4);
        f32x4 xv = *(const f32x4*)(xoX + ((size_t)tLoc * 256 + R0 + row) * NPAD + P0 + u * 4);
        f32x4 bc = *(const f32x4*)(bcp + P0 + u * 4);
        int ll = (U0 + u) >> 7;
        float fmv = fmim_s[row * 16 + ll];
        float imv = fmim_s[row * 16 + 8 + ll];
        size_t ca = (size_t)(R0 + row) * 1024 + U0 + u;
        float cl = cSt[ca];
        float f  = sigf(g[0] + xv[0] + bc[0]);
        float ig = sigf(g[1] + xv[1] + bc[1]);
        float og = sigf(g[2] + xv[2] + bc[2]);
        float ci = tanhf(g[3] + xv[3] + bc[3]);
        float OV = fmv * imv;
        float cn = OV * (f * cl + ig * ci) + (fmv - OV) * cl + (imv - OV) * ci;
        float hn = og * tanhf(cn);
        cSt[ca] = cn;
        ushort hi = f2bf(hn);
        hOut_s[row * 32 + u] = hi;
        loOut_s[row * 32 + u] = f2bf(hn - bf2f(hi));
    }
    __syncthreads();
    {
        int slot = (t + 9) % RING;
        if (tid < 128) {
            int r = tid >> 2, ch = tid & 3;
            *(f32x4*)(hR + (size_t)slot * BH2 + (size_t)(R0 + r) * 2048 + U0 + ch * 8) =
                *(f32x4*)(hOut_s + r * 32 + ch * 8);
        } else {
            int r = (tid - 128) >> 2, ch = tid & 3;
            *(f32x4*)(hR + (size_t)slot * BH2 + (size_t)(R0 + r) * 2048 + 1024 + U0 + ch * 8) =
                *(f32x4*)(loOut_s + r * 32 + ch * 8);
        }
    }
}

// ================= generic bf16 MFMA GEMM (x-part + phase 2) =================
template<int WR, int WC, int AMODE, int EPI>
__global__ __launch_bounds__(WR * WC * 64) void mm_kernel(
    const ushort* __restrict__ A, const ushort* __restrict__ hR,
    const ushort* __restrict__ BT, const float* __restrict__ bias,
    void* __restrict__ Cp, const float* __restrict__ ldw,
    const ushort* __restrict__ TH, float* __restrict__ outp,
    int ldaA, int ldb, int ldc, int K, int t, int RING, int tBase)
{
    constexpr int BM = WR * 64, BN = WC * 64, NT = WR * WC * 64, LS = 72;
    constexpr int AIT = BM * 8 / NT, BIT = BN * 8 / NT;
    __shared__ ushort As[BM * LS];
    __shared__ ushort Bs[BN * LS];
    const int tid = threadIdx.x;
    const int lane = tid & 63, wave = tid >> 6;
    const int wr = wave / WC, wc = wave % WC;

    int bx, by;
    if (AMODE == 2) {
        int vid = blockIdx.x;
        bx = (vid >> 3) & 7;
        by = ((vid >> 6) << 3) + (vid & 7);
        if (by >= t) return;        // t carries nM
    } else {
        bx = blockIdx.x; by = blockIdx.y;
    }
    const int m0 = by * BM, n0 = bx * BN;
    f32x4 acc[4][4] = {};

    auto gather = [&](int ktl, short8* vA, short8* vB) {
#pragma unroll
        for (int i = 0; i < AIT; ++i) {
            int id = tid + i * NT;
            int r = id >> 3, cc = id & 7;
            int k = ktl + cc * 8;
            short8 v;
            if (AMODE == 0) {
                v = *(const short8*)(A + (size_t)(m0 + r) * ldaA + k);
            } else {  // conv gather
                int ks = k >> 10, c = k & 1023;
                int tt = m0 >> 8, b = (m0 & 255) + r;
                int slot = (tBase + tt + ks) % RING;
                short8 hv = *(const short8*)(hR + (size_t)slot * BH2 + (size_t)b * 2048 + c);
                float s = ldw[((size_t)tt * 256 + b) * CSW + ks];
                ushort* pv = (ushort*)&hv;
                ushort* po = (ushort*)&v;
#pragma unroll
                for (int j = 0; j < 8; ++j) po[j] = f2bf(bf2f(pv[j]) * s);
            }
            vA[i] = v;
        }
#pragma unroll
        for (int i = 0; i < BIT; ++i) {
            int id = tid + i * NT;
            int n = id >> 3, cc = id & 7;
            vB[i] = *(const short8*)(BT + (size_t)(n0 + n) * ldb + ktl + cc * 8);
        }
    };

    short8 vA[AIT], vB[BIT];
    gather(0, vA, vB);

    for (int kt = 0; kt < K; kt += 64) {
#pragma unroll
        for (int i = 0; i < AIT; ++i) {
            int id = tid + i * NT;
            *(short8*)(As + (id >> 3) * LS + (id & 7) * 8) = vA[i];
        }
#pragma unroll
        for (int i = 0; i < BIT; ++i) {
            int id = tid + i * NT;
            *(short8*)(Bs + (id >> 3) * LS + (id & 7) * 8) = vB[i];
        }
        __syncthreads();
        if (kt + 64 < K) gather(kt + 64, vA, vB);
#pragma unroll
        for (int kf = 0; kf < 2; ++kf) {
            short8 aF[4], bF[4];
#pragma unroll
            for (int mi = 0; mi < 4; ++mi)
                aF[mi] = *(const short8*)(As + (wr * 64 + mi * 16 + (lane & 15)) * LS + kf * 32 + (lane >> 4) * 8);
#pragma unroll
            for (int ni = 0; ni < 4; ++ni)
                bF[ni] = *(const short8*)(Bs + (wc * 64 + ni * 16 + (lane & 15)) * LS + kf * 32 + (lane >> 4) * 8);
#pragma unroll
            for (int mi = 0; mi < 4; ++mi)
#pragma unroll
                for (int ni = 0; ni < 4; ++ni)
                    acc[mi][ni] = __builtin_amdgcn_mfma_f32_16x16x32_bf16(aF[mi], bF[ni], acc[mi][ni], 0, 0, 0);
        }
        __syncthreads();
    }
#pragma unroll
    for (int mi = 0; mi < 4; ++mi) {
#pragma unroll
        for (int ni = 0; ni < 4; ++ni) {
#pragma unroll
            for (int j = 0; j < 4; ++j) {
                int row = m0 + wr * 64 + mi * 16 + ((lane >> 4) << 2) + j;
                int col = n0 + wc * 64 + ni * 16 + (lane & 15);
                float v = acc[mi][ni][j];
                if (EPI != 0 && bias) v += bias[col];
                if (EPI == 0) {
                    ((float*)Cp)[(size_t)row * ldc + col] = v;
                } else if (EPI == 1) {
                    ((ushort*)Cp)[(size_t)row * ldc + col] = f2bf(v > 0.f ? v : 0.f);
                } else if (EPI == 2) {
                    ((ushort*)Cp)[(size_t)row * ldc + col] = f2bf(sigf(v));
                } else if (EPI == 3) {
                    int tt = row >> 8, b = row & 255;
                    int slot = (tBase + tt + 9) % RING;
                    float th = bf2f(TH[(size_t)row * HH + col]);
                    float h = bf2f(hR[(size_t)slot * BH2 + (size_t)b * 2048 + col]);
                    ((ushort*)Cp)[(size_t)row * ldc + col] = f2bf(th * v + h);
                } else {
                    int tt = tBase + (row >> 8), b = row & 255;
                    outp[((size_t)b * TT + tt) * OUTW + col] = sigf(v);
                }
            }
        }
    }
}

// ================= weight / input prep =================
__device__ __forceinline__ int pcol_to_orig(int n) {
    if (n < 4096) return 16 + (n & 3) * 1024 + (n >> 2);
    if (n < 4112) return n - 4096;
    return -1;
}

__global__ void build_whlP(const float* __restrict__ rw,
                           ushort* __restrict__ WhiP, ushort* __restrict__ WloP)
{
    size_t i = (size_t)blockIdx.x * 256 + threadIdx.x;
    if (i >= (size_t)4096 * 1024) return;
    int pc = (int)(i >> 10), k = (int)(i & 1023);
    int n = 16 + (pc & 3) * 1024 + (pc >> 2);
    float w = rw[(size_t)k * GG + n];
    ushort hi = f2bf(w);
    WhiP[i] = hi;
    WloP[i] = f2bf(w - bf2f(hi));
}

__global__ void build_wsp(const float* __restrict__ rw, ushort* __restrict__ WspT)
{
    int i = blockIdx.x * 256 + threadIdx.x;
    if (i >= 16 * 1024) return;
    int r = i >> 10, k = i & 1023;
    float w = rw[(size_t)k * GG + r];
    ushort hi = f2bf(w);
    WspT[i] = hi;
    WspT[16 * 1024 + i] = f2bf(w - bf2f(hi));
}

__global__ void build_wxt(const float* __restrict__ kw, const float* __restrict__ rw,
                          ushort* __restrict__ WxT)
{
    size_t i = (size_t)blockIdx.x * 256 + threadIdx.x;
    if (i >= (size_t)NPAD * KXP) return;
    int n = (int)(i / KXP), k = (int)(i % KXP);
    int seg = k / 288, kk = k - seg * 288;
    int oc = pcol_to_orig(n);
    float w = 0.f;
    if (oc >= 0 && seg < 3) {
        if (kk < 256)       w = kw[(size_t)kk * GG + oc];
        else if (kk == 256) w = kw[(size_t)256 * GG + oc];
        else if (kk == 257) w = rw[(size_t)1024 * GG + oc];
    }
    ushort hi = f2bf(w);
    WxT[i] = (seg == 1) ? f2bf(w - bf2f(hi)) : hi;
}

__global__ void build_bcp(const float* __restrict__ kb, const float* __restrict__ rb,
                          float* __restrict__ bcp)
{
    int i = blockIdx.x * 256 + threadIdx.x;
    if (i >= NPAD) return;
    int oc = pcol_to_orig(i);
    bcp[i] = (oc >= 0) ? kb[oc] + rb[oc] : 0.f;
}

__global__ void build_xac(const float* __restrict__ x, const float* __restrict__ tim,
                          ushort* __restrict__ XAc, int tBase, int Mloc)
{
    size_t i = (size_t)blockIdx.x * 256 + threadIdx.x;
    if (i >= (size_t)Mloc * KXP) return;
    int m = (int)(i / KXP), k = (int)(i % KXP);
    int t = tBase + (m >> 8), b = m & 255;
    int seg = k / 288, kk = k - seg * 288;
    float v = 0.f;
    if (seg < 3) {
        if (kk < 256)      v = x[((size_t)b * TT + t) * INW + kk];
        else if (kk < 258) v = tim[(size_t)b * TT + t];
    }
    ushort hi = f2bf(v);
    XAc[i] = (seg == 2) ? f2bf(v - bf2f(hi)) : hi;
}

__global__ void build_ctt(const float* __restrict__ cw, ushort* __restrict__ ctT)
{
    size_t i = (size_t)blockIdx.x * 256 + threadIdx.x;
    if (i >= (size_t)HH * HH * CSW) return;
    int o = (int)(i / (HH * CSW)), rest = (int)(i % (HH * CSW));
    int k = rest >> 10, c = rest & 1023;
    ctT[i] = f2bf(cw[((size_t)o * HH + c) * CSW + k]);
}

__global__ void build_swt(const float* __restrict__ sw, const float* __restrict__ sb,
                          ushort* __restrict__ swT, float* __restrict__ sbP)
{
    int i = blockIdx.x * 256 + threadIdx.x;
    if (i < 256 * 1024) {
        int n = i >> 10, k = i & 1023;
        swT[i] = f2bf(n < 170 ? sw[(size_t)k * 170 + n] : 0.f);
    }
    if (i < 256) sbP[i] = (i < 170) ? sb[i] : 0.f;
}

__global__ void build_rswt(const float* __restrict__ rsw, ushort* __restrict__ rswT)
{
    int i = blockIdx.x * 256 + threadIdx.x;
    if (i >= 1024 * 256) return;
    int n = i >> 8, k = i & 255;
    rswT[i] = f2bf(k < 170 ? rsw[(size_t)k * HH + n] : 0.f);
}

__global__ void build_owt(const float* __restrict__ ow, ushort* __restrict__ owT)
{
    int i = blockIdx.x * 256 + threadIdx.x;
    if (i >= OUTW * HH) return;
    int n = i >> 10, k = i & 1023;
    owT[i] = f2bf(ow[(size_t)k * OUTW + n]);
}

// ================= chunk helpers =================
__global__ void ld_chunk_kernel(const float* __restrict__ dist, float* __restrict__ ldC,
                                int tBase, int Mloc)
{
    int id = blockIdx.x * 256 + threadIdx.x;
    if (id >= Mloc) return;
    int t = tBase + (id >> 8), b = id & 255;
    float cv[CSW], cum = 0.f, mx = -1e30f;
#pragma unroll
    for (int k = 0; k < CSW; ++k) {
        int ts = t - 9 + k;
        cum += (ts >= 0) ? dist[(size_t)ts * BB + b] : 0.f;
        cv[k] = cum; mx = fmaxf(mx, cum);
    }
    float ss = 0.f;
#pragma unroll
    for (int k = 0; k < CSW; ++k) { cv[k] = expf(cv[k] - mx); ss += cv[k]; }
    float inv = 1.0f / ss;
#pragma unroll
    for (int k = 0; k < CSW; ++k) ldC[(size_t)id * CSW + k] = cv[k] * inv;
}

__global__ void mlh_kernel(const ushort* __restrict__ hR, const float* __restrict__ ldC,
                           ushort* __restrict__ MLH, int tBase, int RING)
{
    size_t id = (size_t)blockIdx.x * 256 + threadIdx.x;
    int m = (int)(id >> 7);
    int c0 = ((int)(id & 127)) << 3;
    int t = tBase + (m >> 8), b = m & 255;
    float acc[8] = {};
#pragma unroll
    for (int k = 0; k < CSW; ++k) {
        float s = ldC[(size_t)m * CSW + k];
        int slot = (t + k) % RING;
        short8 hv = *(const short8*)(hR + (size_t)slot * BH2 + (size_t)b * 2048 + c0);
        ushort* pv = (ushort*)&hv;
#pragma unroll
        for (int j = 0; j < 8; ++j) acc[j] += bf2f(pv[j]) * s;
    }
#pragma unroll
    for (int j = 0; j < 8; ++j) MLH[(size_t)m * HH + c0 + j] = f2bf(acc[j] * 0.1f);
}

// ================= launch =================
extern "C" void kernel_launch(void* const* d_in, const int* in_sizes, int n_in,
                              void* d_out, int out_size, void* d_ws, size_t ws_size,
                              hipStream_t stream)
{
    const float* x   = (const float*)d_in[0];
    const float* tim = (const float*)d_in[1];
    const float* kw  = (const float*)d_in[2];
    const float* kb  = (const float*)d_in[3];
    const float* rw  = (const float*)d_in[4];
    const float* rb  = (const float*)d_in[5];
    const float* sw  = (const float*)d_in[6];
    const float* sb  = (const float*)d_in[7];
    const float* rsw = (const float*)d_in[8];
    const float* rsb = (const float*)d_in[9];
    const float* cw  = (const float*)d_in[10];
    const float* cb  = (const float*)d_in[11];
    const float* ow  = (const float*)d_in[12];
    const float* ob  = (const float*)d_in[13];
    float* out  = (float*)d_out;
    float* dist = out + (size_t)BB * TT * OUTW;

    auto planSize = [&](int tch) -> size_t {
        size_t o = 0;
        auto al = [&](size_t bytes) { o += (bytes + 255) & ~(size_t)255; };
        int ring = tch + 9;
        al((size_t)ring * BH2 * 2);            // hRing (hi|lo)
        al((size_t)BB * HH * 4);               // cSt
        al((size_t)4096 * 1024 * 2);           // WhiP
        al((size_t)4096 * 1024 * 2);           // WloP
        al((size_t)32 * 1024 * 2);             // WspT
        al((size_t)NPAD * KXP * 2);            // WxT
        al((size_t)NPAD * 4);                  // bcp
        al((size_t)tch * 256 * NPAD * 4);      // xoX
        al((size_t)tch * 256 * KXP * 2);       // XAc
        al((size_t)tch * 256 * CSW * 4);       // ldC
        al((size_t)HH * HH * CSW * 2);         // ctT
        al((size_t)256 * 1024 * 2);            // swT
        al((size_t)256 * 4);                   // sbP
        al((size_t)1024 * 256 * 2);            // rswT
        al((size_t)OUTW * HH * 2);             // owT
        al((size_t)tch * 256 * HH * 2);        // MLH / RNN
        al((size_t)tch * 256 * 256 * 2);       // TH1
        al((size_t)tch * 256 * HH * 2);        // TH
        return o;
    };
    const int cands[4] = {16, 8, 4, 2};
    int TCH = 0;
    for (int ci = 0; ci < 4; ++ci)
        if (planSize(cands[ci]) <= ws_size) { TCH = cands[ci]; break; }
    if (TCH == 0) return;   // diagnostic: output stays zero -> absmax ~0.83
    const int RING = TCH + 9;
    const int Mloc = TCH * 256;
    const int nM = Mloc / 128;

    char* base = (char*)d_ws;
    size_t off = 0;
    auto alloc = [&](size_t bytes) { char* p = base + off; off += (bytes + 255) & ~(size_t)255; return p; };
    ushort* hRing = (ushort*)alloc((size_t)RING * BH2 * 2);
    float*  cSt   = (float*) alloc((size_t)BB * HH * 4);
    ushort* WhiP  = (ushort*)alloc((size_t)4096 * 1024 * 2);
    ushort* WloP  = (ushort*)alloc((size_t)4096 * 1024 * 2);
    ushort* WspT  = (ushort*)alloc((size_t)32 * 1024 * 2);
    ushort* WxT   = (ushort*)alloc((size_t)NPAD * KXP * 2);
    float*  bcp   = (float*) alloc((size_t)NPAD * 4);
    float*  xoX   = (float*) alloc((size_t)Mloc * NPAD * 4);
    ushort* XAc   = (ushort*)alloc((size_t)Mloc * KXP * 2);
    float*  ldC   = (float*) alloc((size_t)Mloc * CSW * 4);
    ushort* ctT   = (ushort*)alloc((size_t)HH * HH * CSW * 2);
    ushort* swT   = (ushort*)alloc((size_t)256 * 1024 * 2);
    float*  sbP   = (float*) alloc((size_t)256 * 4);
    ushort* rswT  = (ushort*)alloc((size_t)1024 * 256 * 2);
    ushort* owT   = (ushort*)alloc((size_t)OUTW * HH * 2);
    ushort* MLH   = (ushort*)alloc((size_t)Mloc * HH * 2);
    ushort* TH1   = (ushort*)alloc((size_t)Mloc * 256 * 2);
    ushort* TH    = (ushort*)alloc((size_t)Mloc * HH * 2);
    ushort* RNN   = MLH;

    hipMemsetAsync(hRing, 0, (size_t)9 * BH2 * 2, stream);
    hipMemsetAsync(cSt, 0, (size_t)BB * HH * 4, stream);

    build_whlP<<<(int)(((size_t)4096 * 1024 + 255) / 256), 256, 0, stream>>>(rw, WhiP, WloP);
    build_wsp<<<(16 * 1024 + 255) / 256, 256, 0, stream>>>(rw, WspT);
    build_wxt<<<(int)(((size_t)NPAD * KXP + 255) / 256), 256, 0, stream>>>(kw, rw, WxT);
    build_bcp<<<(NPAD + 255) / 256, 256, 0, stream>>>(kb, rb, bcp);
    build_ctt<<<(int)(((size_t)HH * HH * CSW + 255) / 256), 256, 0, stream>>>(cw, ctT);
    build_swt<<<(256 * 1024 + 255) / 256, 256, 0, stream>>>(sw, sb, swT, sbP);
    build_rswt<<<(1024 * 256 + 255) / 256, 256, 0, stream>>>(rsw, rswT);
    build_owt<<<(OUTW * HH + 255) / 256, 256, 0, stream>>>(ow, owT);

    for (int tBase = 0; tBase < TT; tBase += TCH) {
        // ---- batched x-part: xoX = XAc @ WxT (permuted N) ----
        build_xac<<<(int)(((size_t)Mloc * KXP + 255) / 256), 256, 0, stream>>>(
            x, tim, XAc, tBase, Mloc);
        mm_kernel<2, 2, 0, 0><<<dim3(33, Mloc / 128), 256, 0, stream>>>(
            XAc, nullptr, WxT, nullptr, xoX, nullptr, nullptr, nullptr,
            KXP, KXP, NPAD, KXP, 0, RING, tBase);
        // ---- fused per-step scan (one dispatch per step, no intra-step sync) ----
        for (int t = tBase; t < tBase + TCH; ++t)
            step_fused<<<256, 256, 0, stream>>>(
                WhiP, WloP, WspT, hRing, cSt, xoX, bcp, dist, t, t - tBase, RING);
        // ---- batched phase-2 ----
        ld_chunk_kernel<<<(Mloc + 255) / 256, 256, 0, stream>>>(dist, ldC, tBase, Mloc);
        mlh_kernel<<<Mloc / 2, 256, 0, stream>>>(hRing, ldC, MLH, tBase, RING);
        mm_kernel<2, 2, 0, 1><<<dim3(2, Mloc / 128), 256, 0, stream>>>(
            MLH, nullptr, swT, sbP, TH1, nullptr, nullptr, nullptr,
            1024, 1024, 256, 1024, 0, RING, tBase);
        mm_kernel<2, 2, 0, 2><<<dim3(8, Mloc / 128), 256, 0, stream>>>(
            TH1, nullptr, rswT, rsb, TH, nullptr, nullptr, nullptr,
            256, 256, 1024, 256, 0, RING, tBase);
        mm_kernel<2, 2, 2, 3><<<dim3(((nM + 7) / 8) * 64), 256, 0, stream>>>(
            nullptr, hRing, ctT, cb, RNN, ldC, TH, nullptr,
            0, HH * CSW, 1024, HH * CSW, nM, RING, tBase);
        mm_kernel<4, 1, 0, 4><<<dim3(1, Mloc / 256), 256, 0, stream>>>(
            RNN, nullptr, owT, ob, nullptr, nullptr, nullptr, out,
            1024, 1024, 0, 1024, 0, RING, tBase);
    }
}

// Round 13
// 13803.233 us; speedup vs baseline: 1.7193x; 1.7193x over previous
//
#include <hip/hip_runtime.h>
#include <hip/hip_bf16.h>
#include <math.h>

#define BB 256
#define TT 256
#define INW 256
#define HH 1024
#define LL 8
#define CSW 10
#define OUTW 64
#define GG 4112
#define KH 1024            // recurrent K
#define KXP 896            // x-part GEMM K: 3*288 = 864 padded
#define NPAD 4224          // 4112 padded to 33*128
#define BH (BB * HH)       // h ring slot stride (hi only)
#define SPL ((size_t)BB * NPAD)

typedef __attribute__((ext_vector_type(8))) short short8;
typedef __attribute__((ext_vector_type(4))) float f32x4;

__device__ __forceinline__ float bf2f(ushort u) {
    union { float f; unsigned int i; } v; v.i = ((unsigned int)u) << 16; return v.f;
}
__device__ __forceinline__ ushort f2bf(float f) {
    __hip_bfloat16 h = __float2bfloat16(f);
    return *(ushort*)&h;
}
__device__ __forceinline__ float sigf(float v) { return 1.0f / (1.0f + expf(-v)); }

// ================= generic bf16 MFMA GEMM =================
// AMODE 0: plain bf16 A (rows contiguous at ldaA)
// AMODE 1: recurrent dual-stream at step t: 33 Whi panels x (mt x khalf) = 132 blocks,
//          panel-pinned (p = vid&7 + 8j). acc += hHi*Whi + hLo*Whi over K=512 half.
//          kh==0 epilogue folds xoX + bc; partials to xoP[kh].
// AMODE 2: conv gather (m-tile-pinned 1-D grid; nM via t)
// EPI 0: fp32 store (AMODE1: split-K fold)  1: relu->bf16  2: sigmoid->bf16
// EPI 3: rnn=TH*(v+bias)+h_t->bf16          4: out sigmoid fp32
template<int WR, int WC, int AMODE, int EPI>
__global__ __launch_bounds__(WR * WC * 64) void mm_kernel(
    const ushort* __restrict__ A, const ushort* __restrict__ hR,
    const ushort* __restrict__ hLo, const ushort* __restrict__ BT,
    const float* __restrict__ bias, void* __restrict__ Cp,
    const float* __restrict__ ldw, const ushort* __restrict__ TH,
    float* __restrict__ outp, const float* __restrict__ xof,
    int ldaA, int ldb, int ldc, int K, int t, int RING, int tBase, int tLoc)
{
    constexpr int BM = WR * 64, BN = WC * 64, NT = WR * WC * 64, LS = 72;
    constexpr int AIT = BM * 8 / NT, BIT = BN * 8 / NT;
    __shared__ ushort As[BM * LS];
    __shared__ ushort Bs[BN * LS];
    __shared__ ushort Als[AMODE == 1 ? BM * LS : 1];
    const int tid = threadIdx.x;
    const int lane = tid & 63, wave = tid >> 6;
    const int wr = wave / WC, wc = wave % WC;

    int bx, by, kh = 0, kBase = 0;
    if (AMODE == 1) {
        int vid = blockIdx.x;
        int xcd = vid & 7, q = vid >> 3;
        int p = xcd + 8 * (q >> 2);
        if (p >= 33) return;
        int mem = q & 3;
        by = mem >> 1; kh = mem & 1;
        bx = p; kBase = kh * 512;
    } else if (AMODE == 2) {
        int vid = blockIdx.x;
        bx = (vid >> 3) & 7;
        by = ((vid >> 6) << 3) + (vid & 7);
        if (by >= t) return;        // t carries nM
    } else {
        bx = blockIdx.x; by = blockIdx.y;
    }
    const int m0 = by * BM, n0 = bx * BN;
    f32x4 acc[4][4] = {};

    const ushort* Ahi = (AMODE == 1) ? hR + (size_t)((t + 8) % RING) * BH : nullptr;

    auto gather = [&](int ktl, short8* vA, short8* vL, short8* vB) {
#pragma unroll
        for (int i = 0; i < AIT; ++i) {
            int id = tid + i * NT;
            int r = id >> 3, cc = id & 7;
            int k = ktl + cc * 8;
            short8 v;
            if (AMODE == 0) {
                v = *(const short8*)(A + (size_t)(m0 + r) * ldaA + k);
            } else if (AMODE == 1) {
                v = *(const short8*)(Ahi + (size_t)(m0 + r) * HH + kBase + k);
                vL[i] = *(const short8*)(hLo + (size_t)(m0 + r) * HH + kBase + k);
            } else {  // conv gather
                int ks = k >> 10, c = k & 1023;
                int tt = m0 >> 8, b = (m0 & 255) + r;
                int slot = (tBase + tt + ks) % RING;
                short8 hv = *(const short8*)(hR + (size_t)slot * BH + (size_t)b * HH + c);
                float s = ldw[((size_t)tt * 256 + b) * CSW + ks];
                ushort* pv = (ushort*)&hv;
                ushort* po = (ushort*)&v;
#pragma unroll
                for (int j = 0; j < 8; ++j) po[j] = f2bf(bf2f(pv[j]) * s);
            }
            vA[i] = v;
        }
#pragma unroll
        for (int i = 0; i < BIT; ++i) {
            int id = tid + i * NT;
            int n = id >> 3, cc = id & 7;
            vB[i] = *(const short8*)(BT + (size_t)(n0 + n) * ldb + kBase + ktl + cc * 8);
        }
    };

    short8 vA[AIT], vL[AMODE == 1 ? AIT : 1], vB[BIT];
    gather(0, vA, vL, vB);

    for (int kt = 0; kt < K; kt += 64) {
#pragma unroll
        for (int i = 0; i < AIT; ++i) {
            int id = tid + i * NT;
            *(short8*)(As + (id >> 3) * LS + (id & 7) * 8) = vA[i];
            if (AMODE == 1)
                *(short8*)(Als + (id >> 3) * LS + (id & 7) * 8) = vL[i];
        }
#pragma unroll
        for (int i = 0; i < BIT; ++i) {
            int id = tid + i * NT;
            *(short8*)(Bs + (id >> 3) * LS + (id & 7) * 8) = vB[i];
        }
        __syncthreads();
        if (kt + 64 < K) gather(kt + 64, vA, vL, vB);
#pragma unroll
        for (int kf = 0; kf < 2; ++kf) {
            short8 aF[4], bF[4];
#pragma unroll
            for (int mi = 0; mi < 4; ++mi)
                aF[mi] = *(const short8*)(As + (wr * 64 + mi * 16 + (lane & 15)) * LS + kf * 32 + (lane >> 4) * 8);
#pragma unroll
            for (int ni = 0; ni < 4; ++ni)
                bF[ni] = *(const short8*)(Bs + (wc * 64 + ni * 16 + (lane & 15)) * LS + kf * 32 + (lane >> 4) * 8);
#pragma unroll
            for (int mi = 0; mi < 4; ++mi)
#pragma unroll
                for (int ni = 0; ni < 4; ++ni)
                    acc[mi][ni] = __builtin_amdgcn_mfma_f32_16x16x32_bf16(aF[mi], bF[ni], acc[mi][ni], 0, 0, 0);
            if (AMODE == 1) {
                short8 aL[4];
#pragma unroll
                for (int mi = 0; mi < 4; ++mi)
                    aL[mi] = *(const short8*)(Als + (wr * 64 + mi * 16 + (lane & 15)) * LS + kf * 32 + (lane >> 4) * 8);
#pragma unroll
                for (int mi = 0; mi < 4; ++mi)
#pragma unroll
                    for (int ni = 0; ni < 4; ++ni)
                        acc[mi][ni] = __builtin_amdgcn_mfma_f32_16x16x32_bf16(aL[mi], bF[ni], acc[mi][ni], 0, 0, 0);
            }
        }
        __syncthreads();
    }
#pragma unroll
    for (int mi = 0; mi < 4; ++mi) {
#pragma unroll
        for (int ni = 0; ni < 4; ++ni) {
#pragma unroll
            for (int j = 0; j < 4; ++j) {
                int row = m0 + wr * 64 + mi * 16 + ((lane >> 4) << 2) + j;
                int col = n0 + wc * 64 + ni * 16 + (lane & 15);
                float v = acc[mi][ni][j];
                if (AMODE == 1 && EPI == 0) {
                    if (kh == 0)
                        v += xof[((size_t)tLoc * 256 + row) * NPAD + col] + bias[col];
                    ((float*)Cp)[(size_t)kh * SPL + (size_t)row * ldc + col] = v;
                } else {
                    if (EPI != 0 && bias) v += bias[col];
                    if (EPI == 0) {
                        ((float*)Cp)[(size_t)row * ldc + col] = v;
                    } else if (EPI == 1) {
                        ((ushort*)Cp)[(size_t)row * ldc + col] = f2bf(v > 0.f ? v : 0.f);
                    } else if (EPI == 2) {
                        ((ushort*)Cp)[(size_t)row * ldc + col] = f2bf(sigf(v));
                    } else if (EPI == 3) {
                        int tt = row >> 8, b = row & 255;
                        int slot = (tBase + tt + 9) % RING;
                        float th = bf2f(TH[(size_t)row * HH + col]);
                        float h = bf2f(hR[(size_t)slot * BH + (size_t)b * HH + col]);
                        ((ushort*)Cp)[(size_t)row * ldc + col] = f2bf(th * v + h);
                    } else {
                        int tt = tBase + (row >> 8), b = row & 255;
                        outp[((size_t)b * TT + tt) * OUTW + col] = sigf(v);
                    }
                }
            }
        }
    }
}

// ================= weight / input prep =================
__global__ void build_whi(const float* __restrict__ rw, ushort* __restrict__ WhiT)
{
    size_t i = (size_t)blockIdx.x * 256 + threadIdx.x;
    if (i >= (size_t)NPAD * KH) return;
    int n = (int)(i / KH), k = (int)(i % KH);
    WhiT[i] = f2bf((n < GG) ? rw[(size_t)k * GG + n] : 0.f);
}

__global__ void build_wxt(const float* __restrict__ kw, const float* __restrict__ rw,
                          ushort* __restrict__ WxT)
{
    size_t i = (size_t)blockIdx.x * 256 + threadIdx.x;
    if (i >= (size_t)NPAD * KXP) return;
    int n = (int)(i / KXP), k = (int)(i % KXP);
    int seg = k / 288, kk = k - seg * 288;
    float w = 0.f;
    if (n < GG && seg < 3) {
        if (kk < 256)       w = kw[(size_t)kk * GG + n];
        else if (kk == 256) w = kw[(size_t)256 * GG + n];
        else if (kk == 257) w = rw[(size_t)1024 * GG + n];
    }
    ushort hi = f2bf(w);
    WxT[i] = (seg == 1) ? f2bf(w - bf2f(hi)) : hi;
}

__global__ void build_bc(const float* __restrict__ kb, const float* __restrict__ rb,
                         float* __restrict__ bc)
{
    int i = blockIdx.x * 256 + threadIdx.x;
    if (i < NPAD) bc[i] = (i < GG) ? kb[i] + rb[i] : 0.f;
}

__global__ void build_xac(const float* __restrict__ x, const float* __restrict__ tim,
                          ushort* __restrict__ XAc, int tBase, int Mloc)
{
    size_t i = (size_t)blockIdx.x * 256 + threadIdx.x;
    if (i >= (size_t)Mloc * KXP) return;
    int m = (int)(i / KXP), k = (int)(i % KXP);
    int t = tBase + (m >> 8), b = m & 255;
    int seg = k / 288, kk = k - seg * 288;
    float v = 0.f;
    if (seg < 3) {
        if (kk < 256)      v = x[((size_t)b * TT + t) * INW + kk];
        else if (kk < 258) v = tim[(size_t)b * TT + t];
    }
    ushort hi = f2bf(v);
    XAc[i] = (seg == 2) ? f2bf(v - bf2f(hi)) : hi;
}

__global__ void build_ctt(const float* __restrict__ cw, ushort* __restrict__ ctT)
{
    size_t i = (size_t)blockIdx.x * 256 + threadIdx.x;
    if (i >= (size_t)HH * HH * CSW) return;
    int o = (int)(i / (HH * CSW)), rest = (int)(i % (HH * CSW));
    int k = rest >> 10, c = rest & 1023;
    ctT[i] = f2bf(cw[((size_t)o * HH + c) * CSW + k]);
}

__global__ void build_swt(const float* __restrict__ sw, const float* __restrict__ sb,
                          ushort* __restrict__ swT, float* __restrict__ sbP)
{
    int i = blockIdx.x * 256 + threadIdx.x;
    if (i < 256 * 1024) {
        int n = i >> 10, k = i & 1023;
        swT[i] = f2bf(n < 170 ? sw[(size_t)k * 170 + n] : 0.f);
    }
    if (i < 256) sbP[i] = (i < 170) ? sb[i] : 0.f;
}

__global__ void build_rswt(const float* __restrict__ rsw, ushort* __restrict__ rswT)
{
    int i = blockIdx.x * 256 + threadIdx.x;
    if (i >= 1024 * 256) return;
    int n = i >> 8, k = i & 255;
    rswT[i] = f2bf(k < 170 ? rsw[(size_t)k * HH + n] : 0.f);
}

__global__ void build_owt(const float* __restrict__ ow, ushort* __restrict__ owT)
{
    int i = blockIdx.x * 256 + threadIdx.x;
    if (i >= OUTW * HH) return;
    int n = i >> 10, k = i & 1023;
    owT[i] = f2bf(ow[(size_t)k * OUTW + n]);
}

// ================= per-step pointwise: xo = plane0 + plane1 (xoX,bc folded) ====
__global__ __launch_bounds__(256) void step_kernel(
    const float* __restrict__ xoP, float* __restrict__ c,
    ushort* __restrict__ hR, ushort* __restrict__ hLo,
    float* __restrict__ dist, int t, int RING)
{
    int b = blockIdx.x, tid = threadIdx.x;
    const float* x0 = xoP + (size_t)b * NPAD;
    const float* x1 = x0 + SPL;
    __shared__ float fm[LL], im[LL];
    if (tid == 0) {
        float xr[2 * LL];
        for (int l = 0; l < 2 * LL; ++l) xr[l] = x0[l] + x1[l];
        float m1 = -1e30f, m2 = -1e30f;
        for (int l = 0; l < LL; ++l) { m1 = fmaxf(m1, xr[l]); m2 = fmaxf(m2, xr[LL + l]); }
        float e1[LL], e2[LL], s1 = 0.f, s2 = 0.f;
        for (int l = 0; l < LL; ++l) {
            e1[l] = expf(xr[l] - m1); s1 += e1[l];
            e2[l] = expf(xr[LL + l] - m2); s2 += e2[l];
        }
        float cum = 0.f, mean = 0.f;
        for (int l = 0; l < LL; ++l) { cum += e1[l] / s1; fm[l] = cum; mean += cum; }
        float rc = 0.f;
        for (int l = LL - 1; l >= 0; --l) { rc += e2[l] / s2; im[l] = rc; }
        dist[(size_t)t * BB + b] = 1.0f - mean / LL;
    }
    __syncthreads();
    int slot = (t + 9) % RING;
    for (int e = tid; e < HH; e += 256) {
        int l = e >> 7;
        int c0 = 2 * LL + e;
        float f  = sigf(x0[c0] + x1[c0]);
        int c1 = c0 + HH;
        float ig = sigf(x0[c1] + x1[c1]);
        int c2 = c1 + HH;
        float og = sigf(x0[c2] + x1[c2]);
        int c3 = c2 + HH;
        float ci = tanhf(x0[c3] + x1[c3]);
        size_t idx = (size_t)b * HH + e;
        float cl = c[idx];
        float F = fm[l], I = im[l], OV = F * I;
        float cn = OV * (f * cl + ig * ci) + (F - OV) * cl + (I - OV) * ci;
        float hn = og * tanhf(cn);
        c[idx] = cn;
        ushort hi = f2bf(hn);
        hR[(size_t)slot * BH + idx] = hi;
        hLo[idx] = f2bf(hn - bf2f(hi));
    }
}

// ================= chunk helpers =================
__global__ void ld_chunk_kernel(const float* __restrict__ dist, float* __restrict__ ldC,
                                int tBase, int Mloc)
{
    int id = blockIdx.x * 256 + threadIdx.x;
    if (id >= Mloc) return;
    int t = tBase + (id >> 8), b = id & 255;
    float cv[CSW], cum = 0.f, mx = -1e30f;
#pragma unroll
    for (int k = 0; k < CSW; ++k) {
        int ts = t - 9 + k;
        cum += (ts >= 0) ? dist[(size_t)ts * BB + b] : 0.f;
        cv[k] = cum; mx = fmaxf(mx, cum);
    }
    float ss = 0.f;
#pragma unroll
    for (int k = 0; k < CSW; ++k) { cv[k] = expf(cv[k] - mx); ss += cv[k]; }
    float inv = 1.0f / ss;
#pragma unroll
    for (int k = 0; k < CSW; ++k) ldC[(size_t)id * CSW + k] = cv[k] * inv;
}

__global__ void mlh_kernel(const ushort* __restrict__ hR, const float* __restrict__ ldC,
                           ushort* __restrict__ MLH, int tBase, int RING)
{
    size_t id = (size_t)blockIdx.x * 256 + threadIdx.x;
    int m = (int)(id >> 7);
    int c0 = ((int)(id & 127)) << 3;
    int t = tBase + (m >> 8), b = m & 255;
    float acc[8] = {};
#pragma unroll
    for (int k = 0; k < CSW; ++k) {
        float s = ldC[(size_t)m * CSW + k];
        int slot = (t + k) % RING;
        short8 hv = *(const short8*)(hR + (size_t)slot * BH + (size_t)b * HH + c0);
        ushort* pv = (ushort*)&hv;
#pragma unroll
        for (int j = 0; j < 8; ++j) acc[j] += bf2f(pv[j]) * s;
    }
#pragma unroll
    for (int j = 0; j < 8; ++j) MLH[(size_t)m * HH + c0 + j] = f2bf(acc[j] * 0.1f);
}

// ================= launch =================
extern "C" void kernel_launch(void* const* d_in, const int* in_sizes, int n_in,
                              void* d_out, int out_size, void* d_ws, size_t ws_size,
                              hipStream_t stream)
{
    const float* x   = (const float*)d_in[0];
    const float* tim = (const float*)d_in[1];
    const float* kw  = (const float*)d_in[2];
    const float* kb  = (const float*)d_in[3];
    const float* rw  = (const float*)d_in[4];
    const float* rb  = (const float*)d_in[5];
    const float* sw  = (const float*)d_in[6];
    const float* sb  = (const float*)d_in[7];
    const float* rsw = (const float*)d_in[8];
    const float* rsb = (const float*)d_in[9];
    const float* cw  = (const float*)d_in[10];
    const float* cb  = (const float*)d_in[11];
    const float* ow  = (const float*)d_in[12];
    const float* ob  = (const float*)d_in[13];
    float* out  = (float*)d_out;
    float* dist = out + (size_t)BB * TT * OUTW;

    auto planSize = [&](int tch) -> size_t {
        size_t o = 0;
        auto al = [&](size_t bytes) { o += (bytes + 255) & ~(size_t)255; };
        int ring = tch + 9;
        al((size_t)ring * BH * 2);             // hRing (hi)
        al((size_t)BH * 2);                    // hLo
        al((size_t)BH * 4);                    // c
        al((size_t)NPAD * KH * 2);             // WhiT
        al((size_t)NPAD * KXP * 2);            // WxT
        al((size_t)NPAD * 4);                  // bc
        al((size_t)2 * BB * NPAD * 4);         // xoP (2 split-K planes)
        al((size_t)tch * 256 * NPAD * 4);      // xoX
        al((size_t)tch * 256 * KXP * 2);       // XAc
        al((size_t)tch * 256 * CSW * 4);       // ldC
        al((size_t)HH * HH * CSW * 2);         // ctT
        al((size_t)256 * 1024 * 2);            // swT
        al((size_t)256 * 4);                   // sbP
        al((size_t)1024 * 256 * 2);            // rswT
        al((size_t)OUTW * HH * 2);             // owT
        al((size_t)tch * 256 * HH * 2);        // MLH / RNN
        al((size_t)tch * 256 * 256 * 2);       // TH1
        al((size_t)tch * 256 * HH * 2);        // TH
        return o;
    };
    const int cands[5] = {32, 16, 8, 4, 2};
    int TCH = 0;
    for (int ci = 0; ci < 5; ++ci)
        if (planSize(cands[ci]) <= ws_size) { TCH = cands[ci]; break; }
    if (TCH == 0) return;   // diagnostic: output stays zero -> absmax ~0.83
    const int RING = TCH + 9;
    const int Mloc = TCH * 256;
    const int nM = Mloc / 128;

    char* base = (char*)d_ws;
    size_t off = 0;
    auto alloc = [&](size_t bytes) { char* p = base + off; off += (bytes + 255) & ~(size_t)255; return p; };
    ushort* hRing = (ushort*)alloc((size_t)RING * BH * 2);
    ushort* hLo   = (ushort*)alloc((size_t)BH * 2);
    float*  c     = (float*) alloc((size_t)BH * 4);
    ushort* WhiT  = (ushort*)alloc((size_t)NPAD * KH * 2);
    ushort* WxT   = (ushort*)alloc((size_t)NPAD * KXP * 2);
    float*  bc    = (float*) alloc((size_t)NPAD * 4);
    float*  xoP   = (float*) alloc((size_t)2 * BB * NPAD * 4);
    float*  xoX   = (float*) alloc((size_t)Mloc * NPAD * 4);
    ushort* XAc   = (ushort*)alloc((size_t)Mloc * KXP * 2);
    float*  ldC   = (float*) alloc((size_t)Mloc * CSW * 4);
    ushort* ctT   = (ushort*)alloc((size_t)HH * HH * CSW * 2);
    ushort* swT   = (ushort*)alloc((size_t)256 * 1024 * 2);
    float*  sbP   = (float*) alloc((size_t)256 * 4);
    ushort* rswT  = (ushort*)alloc((size_t)1024 * 256 * 2);
    ushort* owT   = (ushort*)alloc((size_t)OUTW * HH * 2);
    ushort* MLH   = (ushort*)alloc((size_t)Mloc * HH * 2);
    ushort* TH1   = (ushort*)alloc((size_t)Mloc * 256 * 2);
    ushort* TH    = (ushort*)alloc((size_t)Mloc * HH * 2);
    ushort* RNN   = MLH;

    hipMemsetAsync(hRing, 0, (size_t)9 * BH * 2, stream);
    hipMemsetAsync(hLo, 0, (size_t)BH * 2, stream);
    hipMemsetAsync(c, 0, (size_t)BH * 4, stream);

    build_whi<<<(int)(((size_t)NPAD * KH + 255) / 256), 256, 0, stream>>>(rw, WhiT);
    build_wxt<<<(int)(((size_t)NPAD * KXP + 255) / 256), 256, 0, stream>>>(kw, rw, WxT);
    build_bc<<<(NPAD + 255) / 256, 256, 0, stream>>>(kb, rb, bc);
    build_ctt<<<(int)(((size_t)HH * HH * CSW + 255) / 256), 256, 0, stream>>>(cw, ctT);
    build_swt<<<(256 * 1024 + 255) / 256, 256, 0, stream>>>(sw, sb, swT, sbP);
    build_rswt<<<(1024 * 256 + 255) / 256, 256, 0, stream>>>(rsw, rswT);
    build_owt<<<(OUTW * HH + 255) / 256, 256, 0, stream>>>(ow, owT);

    for (int tBase = 0; tBase < TT; tBase += TCH) {
        // ---- batched x-part: xoX = XAc @ WxT ----
        build_xac<<<(int)(((size_t)Mloc * KXP + 255) / 256), 256, 0, stream>>>(
            x, tim, XAc, tBase, Mloc);
        mm_kernel<2, 2, 0, 0><<<dim3(33, Mloc / 128), 256, 0, stream>>>(
            XAc, nullptr, nullptr, WxT, nullptr, xoX, nullptr, nullptr, nullptr, nullptr,
            KXP, KXP, NPAD, KXP, 0, RING, tBase, 0);
        // ---- scan: per step, dual-stream split-K GEMM + pointwise ----
        for (int t = tBase; t < tBase + TCH; ++t) {
            mm_kernel<2, 2, 1, 0><<<dim3(160), 256, 0, stream>>>(
                nullptr, hRing, hLo, WhiT, bc, xoP, nullptr, nullptr, nullptr, xoX,
                0, KH, NPAD, 512, t, RING, 0, t - tBase);
            step_kernel<<<BB, 256, 0, stream>>>(xoP, c, hRing, hLo, dist, t, RING);
        }
        // ---- batched phase-2 ----
        ld_chunk_kernel<<<(Mloc + 255) / 256, 256, 0, stream>>>(dist, ldC, tBase, Mloc);
        mlh_kernel<<<Mloc / 2, 256, 0, stream>>>(hRing, ldC, MLH, tBase, RING);
        mm_kernel<2, 2, 0, 1><<<dim3(2, Mloc / 128), 256, 0, stream>>>(
            MLH, nullptr, nullptr, swT, sbP, TH1, nullptr, nullptr, nullptr, nullptr,
            1024, 1024, 256, 1024, 0, RING, tBase, 0);
        mm_kernel<2, 2, 0, 2><<<dim3(8, Mloc / 128), 256, 0, stream>>>(
            TH1, nullptr, nullptr, rswT, rsb, TH, nullptr, nullptr, nullptr, nullptr,
            256, 256, 1024, 256, 0, RING, tBase, 0);
        mm_kernel<2, 2, 2, 3><<<dim3(((nM + 7) / 8) * 64), 256, 0, stream>>>(
            nullptr, hRing, nullptr, ctT, cb, RNN, ldC, TH, nullptr, nullptr,
            0, HH * CSW, 1024, HH * CSW, nM, RING, tBase, 0);
        mm_kernel<4, 1, 0, 4><<<dim3(1, Mloc / 256), 256, 0, stream>>>(
            RNN, nullptr, nullptr, owT, ob, nullptr, nullptr, nullptr, out, nullptr,
            1024, 1024, 0, 1024, 0, RING, tBase, 0);
    }
}